// Round 13
// baseline (168.652 us; speedup 1.0000x reference)
//
#include <hip/hip_runtime.h>
#include <hip/hip_bf16.h>

// GCNConv: out = segment_sum(edge_vals * (x@W)[edge_col], edge_row)
// Phase 1: Wt = bf16(W^T); h = x@W via bf16 MFMA. Column-split: each block
//          does 128 rows x 64 cols (grid x2 -> ~24 waves/CU for latency hiding).
// Phase 2: ATOMIC-FREE bucket counting sort (bucket = 64 rows):
//   hist -> colscan -> basescan -> scatter (LDS atomics only) -> bucket_rowsum
//   (gather unrolled x8).

#define IN_F  256
#define OUT_F 128
#define BSH   6        // 64 rows per bucket
#define CH    4096     // edges per chunk block
#define CAP   1536     // LDS sorted-bucket capacity (avg 1024, +16 sigma)

typedef __attribute__((ext_vector_type(8))) short sh8;
typedef __attribute__((ext_vector_type(4))) float f32x4;

__device__ __forceinline__ unsigned short f2bf(float f) {
    unsigned u = __float_as_uint(f);
    unsigned r = u + 0x7fff + ((u >> 16) & 1);   // round-to-nearest-even
    return (unsigned short)(r >> 16);
}
__device__ __forceinline__ float bf2f(unsigned short s) {
    return __uint_as_float(((unsigned)s) << 16);
}

// ---------------- Wt[n][k] = bf16(W[k][n]) ----------------
__global__ __launch_bounds__(256) void wt_prep_kernel(
    const float* __restrict__ w, unsigned short* __restrict__ wt) {
    int i = blockIdx.x * 256 + threadIdx.x;     // 32768 elements
    int k = i >> 7, n = i & 127;
    wt[n * IN_F + k] = f2bf(w[i]);
}

// ---------------- h = x@W via MFMA, column-split ----------------
// blockIdx.x: row tile (128 rows, 4 waves x 32). blockIdx.y: col half (64).
__global__ __launch_bounds__(256) void gemm_mfma_kernel(
    const float* __restrict__ x, const unsigned short* __restrict__ wt,
    unsigned short* __restrict__ h, int n_nodes) {
    int tid = threadIdx.x;
    int wv = tid >> 6, l = tid & 63;
    int l16 = l & 15, lk = (l >> 4) * 8;
    int ch = blockIdx.y;                          // 0 or 1
    long row0 = (long)blockIdx.x * 128 + wv * 32;

    long rmax = n_nodes - 1;
    long ra0 = row0 + l16;      if (ra0 > rmax) ra0 = rmax;
    long ra1 = row0 + 16 + l16; if (ra1 > rmax) ra1 = rmax;
    const float* xp0 = x + ra0 * IN_F + lk;
    const float* xp1 = x + ra1 * IN_F + lk;
    const unsigned short* wp = wt + (ch * 64 + l16) * IN_F + lk;

    f32x4 acc[2][4];
    #pragma unroll
    for (int rt = 0; rt < 2; rt++)
        #pragma unroll
        for (int nt = 0; nt < 4; nt++)
            acc[rt][nt] = (f32x4){0.f, 0.f, 0.f, 0.f};

    #pragma unroll
    for (int ks = 0; ks < 8; ks++) {
        int k0 = ks * 32;
        float4 t0 = *(const float4*)(xp0 + k0);
        float4 t1 = *(const float4*)(xp0 + k0 + 4);
        float4 t2 = *(const float4*)(xp1 + k0);
        float4 t3 = *(const float4*)(xp1 + k0 + 4);
        sh8 a0, a1;
        a0[0] = (short)f2bf(t0.x); a0[1] = (short)f2bf(t0.y);
        a0[2] = (short)f2bf(t0.z); a0[3] = (short)f2bf(t0.w);
        a0[4] = (short)f2bf(t1.x); a0[5] = (short)f2bf(t1.y);
        a0[6] = (short)f2bf(t1.z); a0[7] = (short)f2bf(t1.w);
        a1[0] = (short)f2bf(t2.x); a1[1] = (short)f2bf(t2.y);
        a1[2] = (short)f2bf(t2.z); a1[3] = (short)f2bf(t2.w);
        a1[4] = (short)f2bf(t3.x); a1[5] = (short)f2bf(t3.y);
        a1[6] = (short)f2bf(t3.z); a1[7] = (short)f2bf(t3.w);
        #pragma unroll
        for (int nt = 0; nt < 4; nt++) {
            sh8 b = *(const sh8*)(wp + nt * 16 * IN_F + k0);
            acc[0][nt] = __builtin_amdgcn_mfma_f32_16x16x32_bf16(
                a0, b, acc[0][nt], 0, 0, 0);
            acc[1][nt] = __builtin_amdgcn_mfma_f32_16x16x32_bf16(
                a1, b, acc[1][nt], 0, 0, 0);
        }
    }

    int rbase = (l >> 4) * 4;
    #pragma unroll
    for (int rt = 0; rt < 2; rt++) {
        #pragma unroll
        for (int j = 0; j < 4; j++) {
            long r = row0 + rt * 16 + rbase + j;
            if (r < n_nodes) {
                unsigned short* hp = h + r * OUT_F + ch * 64 + l16;
                #pragma unroll
                for (int nt = 0; nt < 4; nt++)
                    hp[nt * 16] = f2bf(acc[rt][nt][j]);
            }
        }
    }
}

// ---------------- hist: T[b][k] = #edges of block b in bucket k -----------
__global__ __launch_bounds__(256) void hist_kernel(
    const int* __restrict__ erow, int* __restrict__ T,
    int n_edges, int nbuck) {
    __shared__ int lh[2048];
    int tid = threadIdx.x, b = blockIdx.x;
    for (int k = tid; k < nbuck; k += 256) lh[k] = 0;
    __syncthreads();
    int s = b * CH, e = min(s + CH, n_edges);
    for (int i = s + tid; i < e; i += 256)
        atomicAdd(&lh[erow[i] >> BSH], 1);
    __syncthreads();
    int* Tr = T + (long)b * nbuck;
    for (int k = tid; k < nbuck; k += 256) Tr[k] = lh[k];
}

// ---------------- colscan: T[b][k] -> prefix over b; colTotal[k] ----------
__global__ __launch_bounds__(256) void colscan_kernel(
    int* __restrict__ T, int* __restrict__ colTotal, int nblk, int nbuck) {
    int k = blockIdx.x * 4 + (threadIdx.x >> 6);
    int lane = threadIdx.x & 63;
    if (k >= nbuck) return;
    int carry = 0;
    for (int c = 0; c < nblk; c += 64) {
        int b = c + lane;
        int v = (b < nblk) ? T[(long)b * nbuck + k] : 0;
        int incl = v;
        #pragma unroll
        for (int off = 1; off < 64; off <<= 1) {
            int t = __shfl_up(incl, off);
            if (lane >= off) incl += t;
        }
        if (b < nblk) T[(long)b * nbuck + k] = carry + incl - v;
        carry += __shfl(incl, 63);
    }
    if (lane == 0) colTotal[k] = carry;
}

// ---------------- basescan: bucketBase = exclusive scan(colTotal) ---------
__global__ __launch_bounds__(256) void basescan_kernel(
    const int* __restrict__ colTotal, int* __restrict__ base, int nbuck) {
    __shared__ int s[256];
    int tid = threadIdx.x;
    int loc[8];
    int sum = 0;
    #pragma unroll
    for (int j = 0; j < 8; j++) {
        int i = tid * 8 + j;
        loc[j] = (i < nbuck) ? colTotal[i] : 0;
        sum += loc[j];
    }
    s[tid] = sum;
    __syncthreads();
    for (int off = 1; off < 256; off <<= 1) {
        int t = (tid >= off) ? s[tid - off] : 0;
        __syncthreads();
        s[tid] += t;
        __syncthreads();
    }
    int pre = s[tid] - sum;
    #pragma unroll
    for (int j = 0; j < 8; j++) {
        int i = tid * 8 + j;
        if (i < nbuck) base[i] = pre;
        pre += loc[j];
    }
    if (tid == 255) base[nbuck] = pre;    // == n_edges
}

// ---------------- scatter: exact positions via LDS atomics ----------------
__global__ __launch_bounds__(256) void scatter_kernel(
    const int* __restrict__ erow, const int* __restrict__ ecol,
    const float* __restrict__ eval, const int* __restrict__ T,
    const int* __restrict__ base, unsigned long long* __restrict__ epack,
    int n_edges, int nbuck) {
    __shared__ int lpos[2048];
    int tid = threadIdx.x, b = blockIdx.x;
    const int* Tr = T + (long)b * nbuck;
    for (int k = tid; k < nbuck; k += 256) lpos[k] = base[k] + Tr[k];
    __syncthreads();
    int s = b * CH, e = min(s + CH, n_edges);
    for (int i = s + tid; i < e; i += 256) {
        int r = erow[i];
        int c = ecol[i];
        float v = eval[i];
        int p = atomicAdd(&lpos[r >> BSH], 1);
        epack[p] = ((unsigned long long)__float_as_uint(v) << 32)
                 | ((unsigned)(r & 63) << 17) | (unsigned)c;
    }
}

// ---------------- bucket_rowsum: block/bucket, LDS sort, gather x8 --------
__global__ __launch_bounds__(256) void bucket_rowsum_kernel(
    const unsigned short* __restrict__ h, const int* __restrict__ base,
    const unsigned long long* __restrict__ epack,
    float* __restrict__ out, int n_nodes, int nbuck) {
    __shared__ unsigned long long sorted[CAP];
    __shared__ int lh[64], lo[64], lc[64];
    int tid = threadIdx.x, k = blockIdx.x;
    int s = base[k], e = base[k + 1];
    int size = e - s;
    int wv = tid >> 6, lane = tid & 63;

    if (tid < 64) { lh[tid] = 0; lc[tid] = 0; }
    __syncthreads();
    for (int i = tid; i < size; i += 256) {
        unsigned lo32 = (unsigned)(epack[s + i] & 0xffffffffu);
        atomicAdd(&lh[(lo32 >> 17) & 63], 1);
    }
    __syncthreads();
    if (tid < 64) {
        int v = lh[tid];
        int incl = v;
        #pragma unroll
        for (int off = 1; off < 64; off <<= 1) {
            int t = __shfl_up(incl, off);
            if (lane >= off) incl += t;
        }
        lo[tid] = incl - v;
    }
    __syncthreads();
    bool fits = (size <= CAP);
    if (fits) {
        for (int i = tid; i < size; i += 256) {
            unsigned long long ed = epack[s + i];
            int r = (int)((ed >> 17) & 63);
            int p = atomicAdd(&lc[r], 1) + lo[r];
            sorted[p] = ed;
        }
    }
    __syncthreads();

#define GSTEP(EV)                                                            \
    {                                                                        \
        unsigned hv = *((const unsigned*)(h + (long)((EV) & 0x1ffffu) * OUT_F) + lane); \
        float vv = __uint_as_float((unsigned)((EV) >> 32));                  \
        a0 += vv * bf2f((unsigned short)(hv & 0xffff));                      \
        a1 += vv * bf2f((unsigned short)(hv >> 16));                         \
    }

    for (int rr = 0; rr < 16; rr++) {
        int r = wv * 16 + rr;
        long row = (long)k * 64 + r;
        if (row >= n_nodes) break;
        int rs = lo[r], cnt = lh[r];
        float a0 = 0.f, a1 = 0.f;
        if (fits) {
            int j = 0;
            for (; j + 8 <= cnt; j += 8) {
                unsigned long long e0 = sorted[rs + j];
                unsigned long long e1 = sorted[rs + j + 1];
                unsigned long long e2 = sorted[rs + j + 2];
                unsigned long long e3 = sorted[rs + j + 3];
                unsigned long long e4 = sorted[rs + j + 4];
                unsigned long long e5 = sorted[rs + j + 5];
                unsigned long long e6 = sorted[rs + j + 6];
                unsigned long long e7 = sorted[rs + j + 7];
                GSTEP(e0) GSTEP(e1) GSTEP(e2) GSTEP(e3)
                GSTEP(e4) GSTEP(e5) GSTEP(e6) GSTEP(e7)
            }
            for (; j + 4 <= cnt; j += 4) {
                unsigned long long e0 = sorted[rs + j];
                unsigned long long e1 = sorted[rs + j + 1];
                unsigned long long e2 = sorted[rs + j + 2];
                unsigned long long e3 = sorted[rs + j + 3];
                GSTEP(e0) GSTEP(e1) GSTEP(e2) GSTEP(e3)
            }
            for (; j < cnt; j++) {
                unsigned long long e0 = sorted[rs + j];
                GSTEP(e0)
            }
        } else {
            for (int i = 0; i < size; i++) {
                unsigned long long ed = epack[s + i];
                if ((int)((ed >> 17) & 63) == r) GSTEP(ed)
            }
        }
        float2 o; o.x = a0; o.y = a1;
        *(float2*)(out + row * OUT_F + lane * 2) = o;
    }
#undef GSTEP
}

extern "C" void kernel_launch(void* const* d_in, const int* in_sizes, int n_in,
                              void* d_out, int out_size, void* d_ws, size_t ws_size,
                              hipStream_t stream) {
    const float* x    = (const float*)d_in[0];
    const float* w    = (const float*)d_in[1];
    const int*   erow = (const int*)d_in[2];
    const int*   ecol = (const int*)d_in[3];
    const float* eval = (const float*)d_in[4];
    float* out = (float*)d_out;

    int n_nodes = in_sizes[0] / IN_F;
    int n_edges = in_sizes[2];
    int nbuck = (n_nodes + 63) >> BSH;            // 1563
    int nblk  = (n_edges + CH - 1) / CH;          // 391

    // workspace layout (256B aligned)
    char* p = (char*)d_ws;
    auto alloc = [&](size_t bytes) {
        char* q = p;
        p += (bytes + 255) & ~(size_t)255;
        return q;
    };
    unsigned short* h  = (unsigned short*)alloc((size_t)n_nodes * OUT_F * 2);
    int* T        = (int*)alloc((size_t)nblk * nbuck * 4);
    int* colTotal = (int*)alloc((size_t)nbuck * 4);
    int* base     = (int*)alloc((size_t)(nbuck + 1) * 4);
    unsigned long long* epack = (unsigned long long*)alloc((size_t)n_edges * 8);
    unsigned short* wt = (unsigned short*)alloc((size_t)IN_F * OUT_F * 2);

    wt_prep_kernel<<<dim3((IN_F * OUT_F) / 256), 256, 0, stream>>>(w, wt);
    gemm_mfma_kernel<<<dim3((n_nodes + 127) / 128, 2), 256, 0, stream>>>(
        x, wt, h, n_nodes);

    hist_kernel<<<dim3(nblk), 256, 0, stream>>>(erow, T, n_edges, nbuck);
    colscan_kernel<<<dim3((nbuck + 3) / 4), 256, 0, stream>>>(
        T, colTotal, nblk, nbuck);
    basescan_kernel<<<dim3(1), 256, 0, stream>>>(colTotal, base, nbuck);
    scatter_kernel<<<dim3(nblk), 256, 0, stream>>>(
        erow, ecol, eval, T, base, epack, n_edges, nbuck);

    bucket_rowsum_kernel<<<dim3(nbuck), 256, 0, stream>>>(
        h, base, epack, out, n_nodes, nbuck);
}

// Round 15
// 164.451 us; speedup vs baseline: 1.0255x; 1.0255x over previous
//
#include <hip/hip_runtime.h>
#include <hip/hip_bf16.h>

// GCNConv: out = segment_sum(edge_vals * (x@W)[edge_col], edge_row)
// Phase 1: Wt = bf16(W^T); h = x@W via bf16 MFMA. Column-split (128 rows x
//          64 cols per block) + wt-half staged in LDS (stride-264 pad,
//          uniform bank-group spread) so the K-loop issues only x-loads.
// Phase 2: ATOMIC-FREE bucket counting sort (bucket = 64 rows):
//   hist -> colscan -> basescan -> scatter (LDS atomics only) ->
//   bucket_rowsum (single kernel, gather unrolled x8 — R12 known-good).

#define IN_F  256
#define OUT_F 128
#define BSH   6        // 64 rows per bucket
#define CH    4096     // edges per chunk block
#define CAP   1536     // LDS sorted-bucket capacity (avg 1024, +16 sigma)
#define WLS   264      // wt LDS row stride (ushorts): uniform b128 bank spread

typedef __attribute__((ext_vector_type(8))) short sh8;
typedef __attribute__((ext_vector_type(4))) float f32x4;

__device__ __forceinline__ unsigned short f2bf(float f) {
    unsigned u = __float_as_uint(f);
    unsigned r = u + 0x7fff + ((u >> 16) & 1);   // round-to-nearest-even
    return (unsigned short)(r >> 16);
}
__device__ __forceinline__ float bf2f(unsigned short s) {
    return __uint_as_float(((unsigned)s) << 16);
}

// ---------------- Wt[n][k] = bf16(W[k][n]) ----------------
__global__ __launch_bounds__(256) void wt_prep_kernel(
    const float* __restrict__ w, unsigned short* __restrict__ wt) {
    int i = blockIdx.x * 256 + threadIdx.x;     // 32768 elements
    int k = i >> 7, n = i & 127;
    wt[n * IN_F + k] = f2bf(w[i]);
}

// ---------------- h = x@W via MFMA, column-split, wt in LDS ----------------
// blockIdx.x: row tile (128 rows, 4 waves x 32). blockIdx.y: col half (64).
__global__ __launch_bounds__(256) void gemm_mfma_kernel(
    const float* __restrict__ x, const unsigned short* __restrict__ wt,
    unsigned short* __restrict__ h, int n_nodes) {
    __shared__ unsigned short wl[64 * WLS];       // 33.8 KB
    int tid = threadIdx.x;
    int ch = blockIdx.y;                          // 0 or 1

    // stage wt[ch*64 .. ch*64+63][0..255] -> wl (one shot: 128B per thread)
    {
        int row = tid >> 2, cc = tid & 3;
        const sh8* src = (const sh8*)(wt + (ch * 64 + row) * IN_F + cc * 64);
        sh8* dst = (sh8*)(wl + row * WLS + cc * 64);
        #pragma unroll
        for (int q = 0; q < 8; q++) dst[q] = src[q];
    }
    __syncthreads();

    int wv = tid >> 6, l = tid & 63;
    int l16 = l & 15, lk = (l >> 4) * 8;
    long row0 = (long)blockIdx.x * 128 + wv * 32;

    long rmax = n_nodes - 1;
    long ra0 = row0 + l16;      if (ra0 > rmax) ra0 = rmax;
    long ra1 = row0 + 16 + l16; if (ra1 > rmax) ra1 = rmax;
    const float* xp0 = x + ra0 * IN_F + lk;
    const float* xp1 = x + ra1 * IN_F + lk;
    const unsigned short* wp = wl + l16 * WLS + lk;

    f32x4 acc[2][4];
    #pragma unroll
    for (int rt = 0; rt < 2; rt++)
        #pragma unroll
        for (int nt = 0; nt < 4; nt++)
            acc[rt][nt] = (f32x4){0.f, 0.f, 0.f, 0.f};

    #pragma unroll
    for (int ks = 0; ks < 8; ks++) {
        int k0 = ks * 32;
        float4 t0 = *(const float4*)(xp0 + k0);
        float4 t1 = *(const float4*)(xp0 + k0 + 4);
        float4 t2 = *(const float4*)(xp1 + k0);
        float4 t3 = *(const float4*)(xp1 + k0 + 4);
        sh8 a0, a1;
        a0[0] = (short)f2bf(t0.x); a0[1] = (short)f2bf(t0.y);
        a0[2] = (short)f2bf(t0.z); a0[3] = (short)f2bf(t0.w);
        a0[4] = (short)f2bf(t1.x); a0[5] = (short)f2bf(t1.y);
        a0[6] = (short)f2bf(t1.z); a0[7] = (short)f2bf(t1.w);
        a1[0] = (short)f2bf(t2.x); a1[1] = (short)f2bf(t2.y);
        a1[2] = (short)f2bf(t2.z); a1[3] = (short)f2bf(t2.w);
        a1[4] = (short)f2bf(t3.x); a1[5] = (short)f2bf(t3.y);
        a1[6] = (short)f2bf(t3.z); a1[7] = (short)f2bf(t3.w);
        #pragma unroll
        for (int nt = 0; nt < 4; nt++) {
            sh8 b = *(const sh8*)(wp + nt * 16 * WLS + k0);
            acc[0][nt] = __builtin_amdgcn_mfma_f32_16x16x32_bf16(
                a0, b, acc[0][nt], 0, 0, 0);
            acc[1][nt] = __builtin_amdgcn_mfma_f32_16x16x32_bf16(
                a1, b, acc[1][nt], 0, 0, 0);
        }
    }

    int rbase = (l >> 4) * 4;
    #pragma unroll
    for (int rt = 0; rt < 2; rt++) {
        #pragma unroll
        for (int j = 0; j < 4; j++) {
            long r = row0 + rt * 16 + rbase + j;
            if (r < n_nodes) {
                unsigned short* hp = h + r * OUT_F + ch * 64 + l16;
                #pragma unroll
                for (int nt = 0; nt < 4; nt++)
                    hp[nt * 16] = f2bf(acc[rt][nt][j]);
            }
        }
    }
}

// ---------------- hist: T[b][k] = #edges of block b in bucket k -----------
__global__ __launch_bounds__(256) void hist_kernel(
    const int* __restrict__ erow, int* __restrict__ T,
    int n_edges, int nbuck) {
    __shared__ int lh[2048];
    int tid = threadIdx.x, b = blockIdx.x;
    for (int k = tid; k < nbuck; k += 256) lh[k] = 0;
    __syncthreads();
    int s = b * CH, e = min(s + CH, n_edges);
    for (int i = s + tid; i < e; i += 256)
        atomicAdd(&lh[erow[i] >> BSH], 1);
    __syncthreads();
    int* Tr = T + (long)b * nbuck;
    for (int k = tid; k < nbuck; k += 256) Tr[k] = lh[k];
}

// ---------------- colscan: T[b][k] -> prefix over b; colTotal[k] ----------
__global__ __launch_bounds__(256) void colscan_kernel(
    int* __restrict__ T, int* __restrict__ colTotal, int nblk, int nbuck) {
    int k = blockIdx.x * 4 + (threadIdx.x >> 6);
    int lane = threadIdx.x & 63;
    if (k >= nbuck) return;
    int carry = 0;
    for (int c = 0; c < nblk; c += 64) {
        int b = c + lane;
        int v = (b < nblk) ? T[(long)b * nbuck + k] : 0;
        int incl = v;
        #pragma unroll
        for (int off = 1; off < 64; off <<= 1) {
            int t = __shfl_up(incl, off);
            if (lane >= off) incl += t;
        }
        if (b < nblk) T[(long)b * nbuck + k] = carry + incl - v;
        carry += __shfl(incl, 63);
    }
    if (lane == 0) colTotal[k] = carry;
}

// ---------------- basescan: bucketBase = exclusive scan(colTotal) ---------
__global__ __launch_bounds__(256) void basescan_kernel(
    const int* __restrict__ colTotal, int* __restrict__ base, int nbuck) {
    __shared__ int s[256];
    int tid = threadIdx.x;
    int loc[8];
    int sum = 0;
    #pragma unroll
    for (int j = 0; j < 8; j++) {
        int i = tid * 8 + j;
        loc[j] = (i < nbuck) ? colTotal[i] : 0;
        sum += loc[j];
    }
    s[tid] = sum;
    __syncthreads();
    for (int off = 1; off < 256; off <<= 1) {
        int t = (tid >= off) ? s[tid - off] : 0;
        __syncthreads();
        s[tid] += t;
        __syncthreads();
    }
    int pre = s[tid] - sum;
    #pragma unroll
    for (int j = 0; j < 8; j++) {
        int i = tid * 8 + j;
        if (i < nbuck) base[i] = pre;
        pre += loc[j];
    }
    if (tid == 255) base[nbuck] = pre;    // == n_edges
}

// ---------------- scatter: exact positions via LDS atomics ----------------
__global__ __launch_bounds__(256) void scatter_kernel(
    const int* __restrict__ erow, const int* __restrict__ ecol,
    const float* __restrict__ eval, const int* __restrict__ T,
    const int* __restrict__ base, unsigned long long* __restrict__ epack,
    int n_edges, int nbuck) {
    __shared__ int lpos[2048];
    int tid = threadIdx.x, b = blockIdx.x;
    const int* Tr = T + (long)b * nbuck;
    for (int k = tid; k < nbuck; k += 256) lpos[k] = base[k] + Tr[k];
    __syncthreads();
    int s = b * CH, e = min(s + CH, n_edges);
    for (int i = s + tid; i < e; i += 256) {
        int r = erow[i];
        int c = ecol[i];
        float v = eval[i];
        int p = atomicAdd(&lpos[r >> BSH], 1);
        epack[p] = ((unsigned long long)__float_as_uint(v) << 32)
                 | ((unsigned)(r & 63) << 17) | (unsigned)c;
    }
}

// ---------------- bucket_rowsum: block/bucket, LDS sort, gather x8 --------
__global__ __launch_bounds__(256) void bucket_rowsum_kernel(
    const unsigned short* __restrict__ h, const int* __restrict__ base,
    const unsigned long long* __restrict__ epack,
    float* __restrict__ out, int n_nodes, int nbuck) {
    __shared__ unsigned long long sorted[CAP];
    __shared__ int lh[64], lo[64], lc[64];
    int tid = threadIdx.x, k = blockIdx.x;
    int s = base[k], e = base[k + 1];
    int size = e - s;
    int wv = tid >> 6, lane = tid & 63;

    if (tid < 64) { lh[tid] = 0; lc[tid] = 0; }
    __syncthreads();
    for (int i = tid; i < size; i += 256) {
        unsigned lo32 = (unsigned)(epack[s + i] & 0xffffffffu);
        atomicAdd(&lh[(lo32 >> 17) & 63], 1);
    }
    __syncthreads();
    if (tid < 64) {
        int v = lh[tid];
        int incl = v;
        #pragma unroll
        for (int off = 1; off < 64; off <<= 1) {
            int t = __shfl_up(incl, off);
            if (lane >= off) incl += t;
        }
        lo[tid] = incl - v;
    }
    __syncthreads();
    bool fits = (size <= CAP);
    if (fits) {
        for (int i = tid; i < size; i += 256) {
            unsigned long long ed = epack[s + i];
            int r = (int)((ed >> 17) & 63);
            int p = atomicAdd(&lc[r], 1) + lo[r];
            sorted[p] = ed;
        }
    }
    __syncthreads();

#define GSTEP(EV)                                                            \
    {                                                                        \
        unsigned hv = *((const unsigned*)(h + (long)((EV) & 0x1ffffu) * OUT_F) + lane); \
        float vv = __uint_as_float((unsigned)((EV) >> 32));                  \
        a0 += vv * bf2f((unsigned short)(hv & 0xffff));                      \
        a1 += vv * bf2f((unsigned short)(hv >> 16));                         \
    }

    for (int rr = 0; rr < 16; rr++) {
        int r = wv * 16 + rr;
        long row = (long)k * 64 + r;
        if (row >= n_nodes) break;
        int rs = lo[r], cnt = lh[r];
        float a0 = 0.f, a1 = 0.f;
        if (fits) {
            int j = 0;
            for (; j + 8 <= cnt; j += 8) {
                unsigned long long e0 = sorted[rs + j];
                unsigned long long e1 = sorted[rs + j + 1];
                unsigned long long e2 = sorted[rs + j + 2];
                unsigned long long e3 = sorted[rs + j + 3];
                unsigned long long e4 = sorted[rs + j + 4];
                unsigned long long e5 = sorted[rs + j + 5];
                unsigned long long e6 = sorted[rs + j + 6];
                unsigned long long e7 = sorted[rs + j + 7];
                GSTEP(e0) GSTEP(e1) GSTEP(e2) GSTEP(e3)
                GSTEP(e4) GSTEP(e5) GSTEP(e6) GSTEP(e7)
            }
            for (; j + 4 <= cnt; j += 4) {
                unsigned long long e0 = sorted[rs + j];
                unsigned long long e1 = sorted[rs + j + 1];
                unsigned long long e2 = sorted[rs + j + 2];
                unsigned long long e3 = sorted[rs + j + 3];
                GSTEP(e0) GSTEP(e1) GSTEP(e2) GSTEP(e3)
            }
            for (; j < cnt; j++) {
                unsigned long long e0 = sorted[rs + j];
                GSTEP(e0)
            }
        } else {
            for (int i = 0; i < size; i++) {
                unsigned long long ed = epack[s + i];
                if ((int)((ed >> 17) & 63) == r) GSTEP(ed)
            }
        }
        float2 o; o.x = a0; o.y = a1;
        *(float2*)(out + row * OUT_F + lane * 2) = o;
    }
#undef GSTEP
}

extern "C" void kernel_launch(void* const* d_in, const int* in_sizes, int n_in,
                              void* d_out, int out_size, void* d_ws, size_t ws_size,
                              hipStream_t stream) {
    const float* x    = (const float*)d_in[0];
    const float* w    = (const float*)d_in[1];
    const int*   erow = (const int*)d_in[2];
    const int*   ecol = (const int*)d_in[3];
    const float* eval = (const float*)d_in[4];
    float* out = (float*)d_out;

    int n_nodes = in_sizes[0] / IN_F;
    int n_edges = in_sizes[2];
    int nbuck = (n_nodes + 63) >> BSH;            // 1563
    int nblk  = (n_edges + CH - 1) / CH;          // 391

    // workspace layout (256B aligned)
    char* p = (char*)d_ws;
    auto alloc = [&](size_t bytes) {
        char* q = p;
        p += (bytes + 255) & ~(size_t)255;
        return q;
    };
    unsigned short* h  = (unsigned short*)alloc((size_t)n_nodes * OUT_F * 2);
    int* T        = (int*)alloc((size_t)nblk * nbuck * 4);
    int* colTotal = (int*)alloc((size_t)nbuck * 4);
    int* base     = (int*)alloc((size_t)(nbuck + 1) * 4);
    unsigned long long* epack = (unsigned long long*)alloc((size_t)n_edges * 8);
    unsigned short* wt = (unsigned short*)alloc((size_t)IN_F * OUT_F * 2);

    wt_prep_kernel<<<dim3((IN_F * OUT_F) / 256), 256, 0, stream>>>(w, wt);
    gemm_mfma_kernel<<<dim3((n_nodes + 127) / 128, 2), 256, 0, stream>>>(
        x, wt, h, n_nodes);

    hist_kernel<<<dim3(nblk), 256, 0, stream>>>(erow, T, n_edges, nbuck);
    colscan_kernel<<<dim3((nbuck + 3) / 4), 256, 0, stream>>>(
        T, colTotal, nblk, nbuck);
    basescan_kernel<<<dim3(1), 256, 0, stream>>>(colTotal, base, nbuck);
    scatter_kernel<<<dim3(nblk), 256, 0, stream>>>(
        erow, ecol, eval, T, base, epack, n_edges, nbuck);

    bucket_rowsum_kernel<<<dim3(nbuck), 256, 0, stream>>>(
        h, base, epack, out, n_nodes, nbuck);
}